// Round 3
// baseline (1356.063 us; speedup 1.0000x reference)
//
#include <hip/hip_runtime.h>
#include <hip/hip_fp16.h>

// Problem: B=8, N=512, T=24, D=512, H=8, DK=64, K(conv)=3, PAD=1
//   q = conv1d_time(query, Wq)+bq ; k = conv1d_time(key, Wk)+bk   (K=1536 GEMM)
//   v = value @ Wv^T + bv                                          (K=512 GEMM)
//   per (b,n,h): causal softmax(q k^T / 8) @ v
//   out = x @ Wo^T + bo  (fp32)
// GEMMs: M = B*N*T = 98304, N = 512. fp16 MFMA, fp32 accumulate.
// BM=64, BN=256, BK=64, 8 waves; double-buffered LDS, 2-phase pipeline.

typedef _Float16 f16x8 __attribute__((ext_vector_type(8)));
typedef float    f32x4 __attribute__((ext_vector_type(4)));

__device__ __forceinline__ void gload_lds16(const void* src, void* dst) {
    __builtin_amdgcn_global_load_lds(
        (const __attribute__((address_space(1))) void*)src,
        (__attribute__((address_space(3))) void*)dst, 16, 0, 0);
}

// ---------------------------------------------------------------------------
// Weight prep: Wq/Wk (D,D,1,3) -> fp16 [o][k*512+i]; Wv/Wo (D,D) -> fp16 cast
// ---------------------------------------------------------------------------
__global__ __launch_bounds__(512) void prep_weights(
    const float* __restrict__ Wq, const float* __restrict__ Wk,
    const float* __restrict__ Wv, const float* __restrict__ Wo,
    __half* __restrict__ Wq2, __half* __restrict__ Wk2,
    __half* __restrict__ Wv2, __half* __restrict__ Wo2)
{
    int i = blockIdx.x * 512 + threadIdx.x;   // grid covers 1,048,576 exactly
    if (i < 786432) {                          // 512*1536
        int o = i / 1536, r = i - o * 1536;
        int k = r >> 9, c = r & 511;
        int src = o * 1536 + c * 3 + k;        // Wq[o][c][0][k]
        Wq2[i] = __float2half(Wq[src]);
        Wk2[i] = __float2half(Wk[src]);
    } else {
        int j = i - 786432;                    // < 262144 = 512*512
        Wv2[j] = __float2half(Wv[j]);
        Wo2[j] = __float2half(Wo[j]);
    }
}

// ---------------------------------------------------------------------------
// GEMM: C[m][n] = sum_k A[m][k]*B[n][k] + bias[n]
// grid = (M/64, 512/256); 512 threads = 8 waves; wave w owns n-cols
// [nt*256 + w*32, +32). B (and A for MODE 2) staged via global_load_lds
// (linear LDS dest + pre-swizzled source; XOR-by-(row&7) involution).
// MODE 0: A = fp32 conv source (3 taps over t); MODE 1: A = fp32 row-major;
// MODE 2: A = fp16 row-major. 2-phase: stage(t+1) overlaps MFMA(t);
// reg-staged A uses T14 split (issue loads early, cvt+ds_write after MFMA).
// ---------------------------------------------------------------------------
template<int MODE, int KDIM, bool OUTF32>
__global__ __launch_bounds__(512, 4) void gemm_kernel(
    const void* __restrict__ Ap, const __half* __restrict__ Bw,
    const float* __restrict__ bias, void* __restrict__ Cp)
{
    __shared__ __half As[2][64 * 64];     // 2 x 8 KB
    __shared__ __half Bs[2][256 * 64];    // 2 x 32 KB   (total 80 KB)

    const int tid  = threadIdx.x;
    const int lane = tid & 63;
    const int w    = tid >> 6;
    const int l15  = lane & 15, l4 = lane >> 4;
    const int mt   = blockIdx.x;
    const int nt   = blockIdx.y;

    // pre-swizzled per-lane source coords for global_load_lds:
    // lane l -> row_in_chunk = l>>3, fetches global slot (l&7)^(l>>3); lands
    // at linear LDS chunk_base + l*16 == row*128 + (l&7)*16 (swizzled pos).
    const int rin  = lane >> 3;
    const int sfet = (lane & 7) ^ rin;

    // B staging: wave w stages chunks w*4+c (c=0..3), chunk = 8 rows x 128B
    const char* Bsrc = (const char*)Bw
        + ((size_t)(nt * 256 + w * 32) + rin) * (KDIM * 2)
        + (size_t)sfet * 16;
    // A staging via global_load_lds (MODE 2): wave w stages chunk w
    const char* Asrc_lds = (const char*)Ap
        + ((size_t)(mt * 64 + w * 8) + rin) * (KDIM * 2)
        + (size_t)sfet * 16;

    // A reg-staged coords (MODE 0/1): 1 unit of 16B per thread
    const int arow  = tid >> 3;        // 0..63
    const int aslot = tid & 7;         // 0..7
    const int am    = mt * 64 + arow;
    const int abn   = am / 24;
    const int at    = am - abn * 24;
    const int assw  = aslot ^ (arow & 7);

    f32x4 acc[4][2] = {};
    float4 av0, av1;
    bool avalid = false;

    auto a_issue = [&](int kt) {
        const float* A = (const float*)Ap;
        const float* src;
        if (MODE == 0) {
            const int tap = kt >> 3;               // 0..2 (8 K-steps per tap)
            const int ib  = (kt & 7) << 6;         // channel base within tap
            const int ts  = at + tap - 1;
            avalid = ((unsigned)ts < 24u);
            src = avalid ? (A + ((size_t)abn * 24 + ts) * 512 + ib + (aslot << 3))
                         : A;                      // safe dummy, zeroed on write
        } else {
            avalid = true;
            src = A + (size_t)am * 512 + (kt << 6) + (aslot << 3);
        }
        av0 = *(const float4*)src;
        av1 = *(const float4*)(src + 4);
    };
    auto a_write = [&](int buf) {
        union { _Float16 h[8]; uint4 u; } cv;
        if (avalid) {
            cv.h[0]=(_Float16)av0.x; cv.h[1]=(_Float16)av0.y;
            cv.h[2]=(_Float16)av0.z; cv.h[3]=(_Float16)av0.w;
            cv.h[4]=(_Float16)av1.x; cv.h[5]=(_Float16)av1.y;
            cv.h[6]=(_Float16)av1.z; cv.h[7]=(_Float16)av1.w;
        } else {
            #pragma unroll
            for (int q = 0; q < 8; ++q) cv.h[q] = (_Float16)0.f;
        }
        *(uint4*)((char*)As + buf * 8192 + arow * 128 + assw * 16) = cv.u;
    };
    auto stage_lds = [&](int buf, int kt) {
        if constexpr (MODE == 2) {
            gload_lds16(Asrc_lds + ((size_t)kt << 7),
                        (char*)As + buf * 8192 + w * 1024);
        }
        #pragma unroll
        for (int c = 0; c < 4; ++c) {
            gload_lds16(Bsrc + (size_t)c * (8 * KDIM * 2) + ((size_t)kt << 7),
                        (char*)Bs + buf * 32768 + (w * 4 + c) * 1024);
        }
    };

    constexpr int nsteps = KDIM >> 6;

    // prologue: stage kt=0 into buf 0
    if constexpr (MODE != 2) { a_issue(0); a_write(0); }
    stage_lds(0, 0);
    __syncthreads();

    int cur = 0;
    for (int kt = 0; kt < nsteps; ++kt) {
        const bool hn = (kt + 1 < nsteps);
        if (hn) {
            if constexpr (MODE != 2) a_issue(kt + 1);   // loads only (T14 split)
            stage_lds(cur ^ 1, kt + 1);                 // async into other buf
        }
        // ---- compute current buf: 2 k-substeps x 4x2 fragments ----
        #pragma unroll
        for (int ks = 0; ks < 2; ++ks) {
            f16x8 af[4], bf[2];
            #pragma unroll
            for (int mi = 0; mi < 4; ++mi) {
                const int row = mi * 16 + l15;
                const int ss  = ((ks << 2) + l4) ^ (row & 7);
                af[mi] = *(const f16x8*)((const char*)As + cur * 8192
                                         + row * 128 + ss * 16);
            }
            #pragma unroll
            for (int ni = 0; ni < 2; ++ni) {
                const int row = w * 32 + ni * 16 + l15;
                const int ss  = ((ks << 2) + l4) ^ (row & 7);
                bf[ni] = *(const f16x8*)((const char*)Bs + cur * 32768
                                         + row * 128 + ss * 16);
            }
            #pragma unroll
            for (int mi = 0; mi < 4; ++mi)
                #pragma unroll
                for (int ni = 0; ni < 2; ++ni)
                    acc[mi][ni] = __builtin_amdgcn_mfma_f32_16x16x32_f16(
                        af[mi], bf[ni], acc[mi][ni], 0, 0, 0);
        }
        if (hn) { if constexpr (MODE != 2) a_write(cur ^ 1); }  // cvt+ds_write late
        __syncthreads();   // drains stage vmcnt + ds_writes; protects buf reuse
        cur ^= 1;
    }

    // ---- epilogue: + bias, store (C layout: col = lane&15, row = (lane>>4)*4+j)
    #pragma unroll
    for (int ni = 0; ni < 2; ++ni) {
        const int n = nt * 256 + w * 32 + ni * 16 + l15;
        const float bv = bias[n];
        #pragma unroll
        for (int mi = 0; mi < 4; ++mi) {
            #pragma unroll
            for (int j = 0; j < 4; ++j) {
                const size_t m = (size_t)mt * 64 + mi * 16 + l4 * 4 + j;
                const float v = acc[mi][ni][j] + bv;
                if (OUTF32) ((float*)Cp)[m * 512 + n] = v;
                else        ((__half*)Cp)[m * 512 + n] = __float2half(v);
            }
        }
    }
}

// ---------------------------------------------------------------------------
// Attention: 1 wave per (b*n, h) unit. Q,K staged to fp32 LDS (stride 68)
// with vectorized 16B loads; V column in registers (lane = channel e);
// softmax fp32, causal exact. X written over the Q buffer (own slice only).
// ---------------------------------------------------------------------------
__global__ __launch_bounds__(256) void attn_kernel(
    const __half* __restrict__ Q, const __half* __restrict__ K,
    const __half* __restrict__ V, __half* __restrict__ X)
{
    __shared__ float smem[4 * 3864];  // per wave: Qs 24*68, Ks 24*68, Ss 24*25
    const int tid = threadIdx.x, lane = tid & 63, w = tid >> 6;
    float* Qs = smem + w * 3864;
    float* Ks = Qs + 24 * 68;
    float* Ss = Ks + 24 * 68;

    const int unit = blockIdx.x * 4 + w;        // 32768 units
    const int bn = unit >> 3, h = unit & 7;
    const size_t base = (size_t)bn * 24 * 512 + (size_t)h * 64;

    // stage Q,K rows: 24 rows x 64 ch (fp16) = 3KB each -> 3 x 16B per lane
    #pragma unroll
    for (int u = 0; u < 3; ++u) {
        const int idx = u * 64 + lane;          // 0..191
        const int r = idx >> 3, sl = idx & 7;   // row, 8-half slot
        f16x8 qv = *(const f16x8*)(Q + base + r * 512 + sl * 8);
        f16x8 kv = *(const f16x8*)(K + base + r * 512 + sl * 8);
        float4 q0 = { (float)qv[0], (float)qv[1], (float)qv[2], (float)qv[3] };
        float4 q1 = { (float)qv[4], (float)qv[5], (float)qv[6], (float)qv[7] };
        float4 k0 = { (float)kv[0], (float)kv[1], (float)kv[2], (float)kv[3] };
        float4 k1 = { (float)kv[4], (float)kv[5], (float)kv[6], (float)kv[7] };
        *(float4*)&Qs[r * 68 + sl * 8]     = q0;
        *(float4*)&Qs[r * 68 + sl * 8 + 4] = q1;
        *(float4*)&Ks[r * 68 + sl * 8]     = k0;
        *(float4*)&Ks[r * 68 + sl * 8 + 4] = k1;
    }
    // V column into registers (lane = channel; 128B coalesced per instr)
    float vcol[24];
    #pragma unroll
    for (int s = 0; s < 24; ++s)
        vcol[s] = __half2float(V[base + s * 512 + lane]);
    __syncthreads();

    // scores: 576 (t,s) pairs, 9 per lane
    #pragma unroll
    for (int it = 0; it < 9; ++it) {
        const int j = it * 64 + lane;
        const int t = j / 24, s = j - t * 24;
        float a = 0.f;
        #pragma unroll
        for (int e = 0; e < 64; e += 4) {
            float4 qv = *(const float4*)&Qs[t * 68 + e];
            float4 kv = *(const float4*)&Ks[s * 68 + e];
            a += qv.x * kv.x + qv.y * kv.y + qv.z * kv.z + qv.w * kv.w;
        }
        Ss[t * 25 + s] = a * 0.125f;
    }
    __syncthreads();

    // causal softmax, one row per lane (lanes 0..23)
    if (lane < 24) {
        const int t = lane;
        float m = -1e30f;
        for (int s = 0; s <= t; ++s) m = fmaxf(m, Ss[t * 25 + s]);
        float sum = 0.f;
        for (int s = 0; s <= t; ++s) {
            float p = __expf(Ss[t * 25 + s] - m);
            sum += p;
            Ss[t * 25 + s] = p;
        }
        const float inv = 1.f / sum;
        for (int s = 0; s <= t; ++s) Ss[t * 25 + s] *= inv;
    }
    __syncthreads();

    // PV: lane = channel e; P broadcast from LDS
    #pragma unroll
    for (int t = 0; t < 24; ++t) {
        float a = 0.f;
        #pragma unroll
        for (int s = 0; s < 24; ++s) {
            if (s <= t) a += Ss[t * 25 + s] * vcol[s];
        }
        X[base + t * 512 + lane] = __float2half(a);
    }
}

// ---------------------------------------------------------------------------
extern "C" void kernel_launch(void* const* d_in, const int* in_sizes, int n_in,
                              void* d_out, int out_size, void* d_ws, size_t ws_size,
                              hipStream_t stream)
{
    const float* query = (const float*)d_in[0];
    const float* key   = (const float*)d_in[1];
    const float* value = (const float*)d_in[2];
    // d_in[3] = mask (tril(T,T) broadcast) -- causal, implemented directly
    const float* Wq = (const float*)d_in[4];
    const float* bq = (const float*)d_in[5];
    const float* Wk = (const float*)d_in[6];
    const float* bk = (const float*)d_in[7];
    const float* Wv = (const float*)d_in[8];
    const float* bv = (const float*)d_in[9];
    const float* Wo = (const float*)d_in[10];
    const float* bo = (const float*)d_in[11];

    // workspace layout (fp16): Q | K | V | Wq' | Wk' | Wv' | Wo'   (~306 MB)
    char* ws = (char*)d_ws;
    __half* Qb  = (__half*)ws;                          // 98304*512
    __half* Kb  = (__half*)(ws + 100663296);
    __half* Vb  = (__half*)(ws + 201326592);
    __half* Wq2 = (__half*)(ws + 301989888);            // 512*1536
    __half* Wk2 = Wq2 + 786432;
    __half* Wv2 = Wk2 + 786432;                         // 512*512
    __half* Wo2 = Wv2 + 262144;

    prep_weights<<<2048, 512, 0, stream>>>(Wq, Wk, Wv, Wo, Wq2, Wk2, Wv2, Wo2);

    gemm_kernel<0, 1536, false><<<dim3(1536, 2), 512, 0, stream>>>(query, Wq2, bq, Qb);
    gemm_kernel<0, 1536, false><<<dim3(1536, 2), 512, 0, stream>>>(key,   Wk2, bk, Kb);
    gemm_kernel<1,  512, false><<<dim3(1536, 2), 512, 0, stream>>>(value, Wv2, bv, Vb);

    attn_kernel<<<8192, 256, 0, stream>>>(Qb, Kb, Vb, Qb /* X aliases Q */);

    gemm_kernel<2,  512, true><<<dim3(1536, 2), 512, 0, stream>>>(Qb, Wo2, bo, d_out);
}